// Round 3
// baseline (732.416 us; speedup 1.0000x reference)
//
#include <hip/hip_runtime.h>

#define H_ 16
#define HD_ 64
#define S_ 2048
#define D_ 1024
#define B_ 2
#define R_ 32
#define M_ 4096   // B*S
#define N3_ 3072  // 3*D

typedef __attribute__((ext_vector_type(8))) short short8;
typedef __attribute__((ext_vector_type(4))) float f32x4;
typedef unsigned short u16;
typedef __attribute__((ext_vector_type(4))) unsigned short u16x4;

__device__ inline u16 f2bf(float f) {  // RNE float->bf16
  unsigned u = __float_as_uint(f);
  u += 0x7fff + ((u >> 16) & 1);
  return (u16)(u >> 16);
}

// async global->LDS, 16 B per lane; lds ptr must be wave-uniform.
__device__ __forceinline__ void glds16(const u16* g, u16* lds) {
  __builtin_amdgcn_global_load_lds(
      (const __attribute__((address_space(1))) unsigned int*)g,
      (__attribute__((address_space(3))) unsigned int*)lds, 16, 0, 0);
}

// Weff[o*IN+i] = W[o*IN+i] + (1/32) * sum_r A[i*R+r] * Bm[r*OUT+o], stored bf16
__global__ void fold_kernel(const float* __restrict__ W,
                            const float* __restrict__ A,
                            const float* __restrict__ Bm,
                            u16* __restrict__ out, int OUT, int IN) {
  int idx = blockIdx.x * 256 + threadIdx.x;
  int o = idx / IN;
  int i = idx - o * IN;
  float s = 0.f;
#pragma unroll
  for (int r = 0; r < R_; ++r) s += A[i * R_ + r] * Bm[r * OUT + o];
  out[idx] = f2bf(W[idx] + s * (1.0f / 32.0f));
}

__global__ void cvt_kernel(const float* __restrict__ x, u16* __restrict__ xb) {
  int i = (blockIdx.x * 256 + threadIdx.x) * 4;
  const float4 v = *(const float4*)(x + i);
  u16x4 o = {f2bf(v.x), f2bf(v.y), f2bf(v.z), f2bf(v.w)};
  *(u16x4*)(xb + i) = o;
}

// Y[M,N] = X[M,K] @ W[N,K]^T, bf16 in, fp32 acc. 128x128 tile, BK=32,
// global_load_lds width-16 staging (m97 recipe), 4 waves 2x2, 4x4 mfma/wave.
// EPI==0: fp32 Y.  EPI==1: split-store Q,K [b,h,s,d] bf16, V^T [b,h,d,s] bf16.
template <int EPI>
__global__ __launch_bounds__(256) void gemm_bf16(
    const u16* __restrict__ X, const u16* __restrict__ Wb,
    float* __restrict__ Yf, u16* __restrict__ Qb, u16* __restrict__ Kb,
    u16* __restrict__ Vtb, int M, int N, int K) {
  __shared__ u16 As[128 * 32];
  __shared__ u16 Bs[128 * 32];
  const int t = threadIdx.x;
  const int lane = t & 63;
  const int w = t >> 6;
  const int quad = lane >> 4;
  const int l = lane & 15;
  const int wh = w >> 1;
  const int ww = w & 1;
  const int bm = blockIdx.y * 128;
  const int bn = blockIdx.x * 128;
  // staging: wave w owns segments 2w, 2w+1 (16 rows each); lane la stages
  // 16 B chunk (la&3) of row seg*16 + (la>>2).
  const int srow0 = 2 * w * 16 + (lane >> 2);
  const int scol = (lane & 3) * 8;  // u16
  const u16* gA = X + (size_t)(bm + srow0) * K + scol;
  const u16* gB = Wb + (size_t)(bn + srow0) * K + scol;
  const size_t segK = (size_t)16 * K;
  u16* lA0 = As + 2 * w * 512;
  u16* lA1 = lA0 + 512;
  u16* lB0 = Bs + 2 * w * 512;
  u16* lB1 = lB0 + 512;

  f32x4 acc[4][4];
#pragma unroll
  for (int i = 0; i < 4; ++i)
#pragma unroll
    for (int j = 0; j < 4; ++j) acc[i][j] = (f32x4){0.f, 0.f, 0.f, 0.f};

  for (int k0 = 0; k0 < K; k0 += 32) {
    __syncthreads();  // prev tile's ds_reads done
    glds16(gA + k0, lA0);
    glds16(gA + k0 + segK, lA1);
    glds16(gB + k0, lB0);
    glds16(gB + k0 + segK, lB1);
    __syncthreads();  // drains vmcnt -> staged data visible
    short8 af[4], bf[4];
#pragma unroll
    for (int mt = 0; mt < 4; ++mt)
      af[mt] = *(const short8*)&As[(wh * 64 + mt * 16 + l) * 32 + quad * 8];
#pragma unroll
    for (int nt = 0; nt < 4; ++nt)
      bf[nt] = *(const short8*)&Bs[(ww * 64 + nt * 16 + l) * 32 + quad * 8];
#pragma unroll
    for (int mt = 0; mt < 4; ++mt)
#pragma unroll
      for (int nt = 0; nt < 4; ++nt)
        acc[mt][nt] = __builtin_amdgcn_mfma_f32_16x16x32_bf16(
            af[mt], bf[nt], acc[mt][nt], 0, 0, 0);
  }
#pragma unroll
  for (int mt = 0; mt < 4; ++mt) {
#pragma unroll
    for (int nt = 0; nt < 4; ++nt) {
      const int m0 = bm + wh * 64 + mt * 16 + quad * 4;
      const int n = bn + ww * 64 + nt * 16 + l;
      if (EPI == 0) {
#pragma unroll
        for (int r = 0; r < 4; ++r)
          Yf[(size_t)(m0 + r) * N + n] = acc[mt][nt][r];
      } else {
        const int b = m0 >> 11;
        const int s0 = m0 & 2047;
        const int part = n >> 10;
        const int h = (n & 1023) >> 6;
        const int d = n & 63;
        if (part == 0) {
#pragma unroll
          for (int r = 0; r < 4; ++r)
            Qb[((size_t)(b * 16 + h) * 2048 + s0 + r) * 64 + d] =
                f2bf(acc[mt][nt][r]);
        } else if (part == 1) {
#pragma unroll
          for (int r = 0; r < 4; ++r)
            Kb[((size_t)(b * 16 + h) * 2048 + s0 + r) * 64 + d] =
                f2bf(acc[mt][nt][r]);
        } else {
          u16x4 pv = {f2bf(acc[mt][nt][0]), f2bf(acc[mt][nt][1]),
                      f2bf(acc[mt][nt][2]), f2bf(acc[mt][nt][3])};
          *(u16x4*)(Vtb + ((size_t)(b * 16 + h) * 64 + d) * 2048 + s0) = pv;
        }
      }
    }
  }
}

// Flash attention, MFMA, ZERO barriers, batch-fused.
// Block = (q-tile 64, h); 4 waves, wave = 16 q-rows, both batches.
// Q/K/V fragments straight from global; P transpose via wave-private LDS;
// alibi register double-buffered (shared across the two batches).
__global__ __launch_bounds__(256) void attn_mfma(
    const u16* __restrict__ Qb, const u16* __restrict__ Kb,
    const u16* __restrict__ Vtb, const float* __restrict__ alibi,
    const float* __restrict__ pad, u16* __restrict__ ctxb) {
  __shared__ u16 PL[4][16][72];
  const int t = threadIdx.x;
  const int lane = t & 63;
  const int w = t >> 6;
  const int quad = lane >> 4;
  const int l = lane & 15;
  const int q0 = blockIdx.x * 64;
  const int h = blockIdx.y;
  const int qw = q0 + w * 16;

  // Q fragments, both batches
  short8 qf[2][2];
#pragma unroll
  for (int b = 0; b < 2; ++b)
#pragma unroll
    for (int kq = 0; kq < 2; ++kq)
      qf[b][kq] = *(const short8*)(
          Qb + ((size_t)(b * 16 + h) * 2048 + qw + l) * 64 + kq * 32 +
          quad * 8);

  f32x4 Ou[2][4];
  float mrun[2][4], lrun[2][4];
#pragma unroll
  for (int b = 0; b < 2; ++b) {
#pragma unroll
    for (int r = 0; r < 4; ++r) { mrun[b][r] = -1e30f; lrun[b][r] = 0.f; }
#pragma unroll
    for (int dn = 0; dn < 4; ++dn) Ou[b][dn] = (f32x4){0.f, 0.f, 0.f, 0.f};
  }

  const float* ap0 = alibi + ((size_t)h * S_ + qw + quad * 4) * S_ + l;
  float alc[4][4];  // [nt][r], current KV-tile
#pragma unroll
  for (int nt = 0; nt < 4; ++nt)
#pragma unroll
    for (int r = 0; r < 4; ++r)
      alc[nt][r] = ap0[(size_t)r * S_ + nt * 16];

  const u16* Kg0 = Kb + (size_t)h * 2048 * 64;
  const u16* Vg0 = Vtb + (size_t)h * 64 * 2048;
  const size_t bstride = (size_t)16 * 2048 * 64;

  for (int kt = 0; kt < S_ / 64; ++kt) {
    const int k0 = kt * 64;
    float aln[4][4];
    if (kt < S_ / 64 - 1) {  // prefetch next alibi tile (fire-and-forget)
#pragma unroll
      for (int nt = 0; nt < 4; ++nt)
#pragma unroll
        for (int r = 0; r < 4; ++r)
          aln[nt][r] = ap0[(size_t)r * S_ + k0 + 64 + nt * 16];
    }
    float padv[2][4];
#pragma unroll
    for (int b = 0; b < 2; ++b)
#pragma unroll
      for (int nt = 0; nt < 4; ++nt)
        padv[b][nt] = pad[(size_t)b * S_ + k0 + nt * 16 + l];

#pragma unroll
    for (int b = 0; b < 2; ++b) {
      const u16* Kg = Kg0 + (size_t)b * bstride + (size_t)k0 * 64;
      const u16* Vg = Vg0 + (size_t)b * bstride;
      short8 kf[4][2];
#pragma unroll
      for (int nt = 0; nt < 4; ++nt)
#pragma unroll
        for (int kq = 0; kq < 2; ++kq)
          kf[nt][kq] = *(const short8*)(Kg + (size_t)(nt * 16 + l) * 64 +
                                        kq * 32 + quad * 8);
      f32x4 sc[4];
#pragma unroll
      for (int nt = 0; nt < 4; ++nt) {
        f32x4 c = {0.f, 0.f, 0.f, 0.f};
        c = __builtin_amdgcn_mfma_f32_16x16x32_bf16(qf[b][0], kf[nt][0], c, 0, 0, 0);
        c = __builtin_amdgcn_mfma_f32_16x16x32_bf16(qf[b][1], kf[nt][1], c, 0, 0, 0);
        sc[nt] = c;
      }
#pragma unroll
      for (int nt = 0; nt < 4; ++nt)
#pragma unroll
        for (int r = 0; r < 4; ++r)
          sc[nt][r] = fmaf(sc[nt][r], 0.125f, alc[nt][r] + padv[b][nt]);
      // online softmax, rows = quad*4 + r, reduce over 16 l-lanes
#pragma unroll
      for (int r = 0; r < 4; ++r) {
        float rm = fmaxf(fmaxf(sc[0][r], sc[1][r]), fmaxf(sc[2][r], sc[3][r]));
#pragma unroll
        for (int off = 1; off < 16; off <<= 1)
          rm = fmaxf(rm, __shfl_xor(rm, off, 16));
        const float mnew = fmaxf(mrun[b][r], rm);
        const float alpha = __expf(mrun[b][r] - mnew);
        mrun[b][r] = mnew;
        float rs = 0.f;
#pragma unroll
        for (int nt = 0; nt < 4; ++nt) {
          const float e = __expf(sc[nt][r] - mnew);
          sc[nt][r] = e;
          rs += e;
        }
#pragma unroll
        for (int off = 1; off < 16; off <<= 1) rs += __shfl_xor(rs, off, 16);
        lrun[b][r] = lrun[b][r] * alpha + rs;
#pragma unroll
        for (int dn = 0; dn < 4; ++dn) Ou[b][dn][r] *= alpha;
      }
      // P -> wave-private LDS (A-operand layout), same-wave in-order DS
#pragma unroll
      for (int nt = 0; nt < 4; ++nt)
#pragma unroll
        for (int r = 0; r < 4; ++r)
          PL[w][quad * 4 + r][nt * 16 + l] = f2bf(sc[nt][r]);
      short8 vf[4][2];
#pragma unroll
      for (int dn = 0; dn < 4; ++dn)
#pragma unroll
        for (int kq = 0; kq < 2; ++kq)
          vf[dn][kq] = *(const short8*)(Vg + (size_t)(dn * 16 + l) * 2048 +
                                        k0 + kq * 32 + quad * 8);
      short8 pf[2];
#pragma unroll
      for (int kq = 0; kq < 2; ++kq)
        pf[kq] = *(const short8*)&PL[w][l][kq * 32 + quad * 8];
#pragma unroll
      for (int dn = 0; dn < 4; ++dn) {
        Ou[b][dn] = __builtin_amdgcn_mfma_f32_16x16x32_bf16(
            pf[0], vf[dn][0], Ou[b][dn], 0, 0, 0);
        Ou[b][dn] = __builtin_amdgcn_mfma_f32_16x16x32_bf16(
            pf[1], vf[dn][1], Ou[b][dn], 0, 0, 0);
      }
    }
    if (kt < S_ / 64 - 1) {
#pragma unroll
      for (int nt = 0; nt < 4; ++nt)
#pragma unroll
        for (int r = 0; r < 4; ++r) alc[nt][r] = aln[nt][r];
    }
  }

#pragma unroll
  for (int b = 0; b < 2; ++b)
#pragma unroll
    for (int r = 0; r < 4; ++r) {
      const float inv = 1.0f / lrun[b][r];
      const int s = qw + quad * 4 + r;
#pragma unroll
      for (int dn = 0; dn < 4; ++dn)
        ctxb[((size_t)b * 2048 + s) * 1024 + h * 64 + dn * 16 + l] =
            f2bf(Ou[b][dn][r] * inv);
    }
}

extern "C" void kernel_launch(void* const* d_in, const int* in_sizes, int n_in,
                              void* d_out, int out_size, void* d_ws,
                              size_t ws_size, hipStream_t stream) {
  const float* x     = (const float*)d_in[0];
  const float* alibi = (const float*)d_in[1];
  const float* pad   = (const float*)d_in[2];
  const float* W_qkv = (const float*)d_in[3];
  const float* A_qkv = (const float*)d_in[4];
  const float* B_qkv = (const float*)d_in[5];
  const float* W_out = (const float*)d_in[6];
  const float* A_out = (const float*)d_in[7];
  const float* B_out = (const float*)d_in[8];
  float* out = (float*)d_out;

  u16* ws = (u16*)d_ws;
  u16* xb    = ws;                               // 4096*1024
  u16* weffq = xb + (size_t)M_ * D_;             // 3072*1024
  u16* weffo = weffq + (size_t)N3_ * D_;         // 1024*1024
  u16* Qb    = weffo + (size_t)D_ * D_;          // 2*16*2048*64
  u16* Kb    = Qb + (size_t)M_ * D_;
  u16* Vtb   = Kb + (size_t)M_ * D_;
  u16* ctxb  = Vtb + (size_t)M_ * D_;            // 4096*1024

  fold_kernel<<<(N3_ * D_) / 256, 256, 0, stream>>>(W_qkv, A_qkv, B_qkv, weffq,
                                                    N3_, D_);
  fold_kernel<<<(D_ * D_) / 256, 256, 0, stream>>>(W_out, A_out, B_out, weffo,
                                                   D_, D_);
  cvt_kernel<<<(M_ * D_) / 1024, 256, 0, stream>>>(x, xb);
  gemm_bf16<1><<<dim3(N3_ / 128, M_ / 128), 256, 0, stream>>>(
      xb, weffq, nullptr, Qb, Kb, Vtb, M_, N3_, D_);
  attn_mfma<<<dim3(S_ / 64, H_), 256, 0, stream>>>(Qb, Kb, Vtb, alibi, pad,
                                                   ctxb);
  gemm_bf16<0><<<dim3(D_ / 128, M_ / 128), 256, 0, stream>>>(
      ctxb, weffo, out, nullptr, nullptr, nullptr, M_, D_, D_);
}

// Round 4
// 604.471 us; speedup vs baseline: 1.2117x; 1.2117x over previous
//
#include <hip/hip_runtime.h>

#define H_ 16
#define HD_ 64
#define S_ 2048
#define D_ 1024
#define B_ 2
#define R_ 32
#define M_ 4096   // B*S
#define N3_ 3072  // 3*D

typedef __attribute__((ext_vector_type(8))) short short8;
typedef __attribute__((ext_vector_type(4))) float f32x4;
typedef unsigned short u16;
typedef __attribute__((ext_vector_type(4))) unsigned short u16x4;

__device__ inline u16 f2bf(float f) {  // RNE float->bf16
  unsigned u = __float_as_uint(f);
  u += 0x7fff + ((u >> 16) & 1);
  return (u16)(u >> 16);
}

// async global->LDS, 16 B per lane; lds ptr must be wave-uniform.
__device__ __forceinline__ void glds16(const u16* g, u16* lds) {
  __builtin_amdgcn_global_load_lds(
      (const __attribute__((address_space(1))) unsigned int*)g,
      (__attribute__((address_space(3))) unsigned int*)lds, 16, 0, 0);
}

// Weff[o*IN+i] = W[o*IN+i] + (1/32) * sum_r A[i*R+r] * Bm[r*OUT+o], stored bf16
__global__ void fold_kernel(const float* __restrict__ W,
                            const float* __restrict__ A,
                            const float* __restrict__ Bm,
                            u16* __restrict__ out, int OUT, int IN) {
  int idx = blockIdx.x * 256 + threadIdx.x;
  int o = idx / IN;
  int i = idx - o * IN;
  float s = 0.f;
#pragma unroll
  for (int r = 0; r < R_; ++r) s += A[i * R_ + r] * Bm[r * OUT + o];
  out[idx] = f2bf(W[idx] + s * (1.0f / 32.0f));
}

__global__ void cvt_kernel(const float* __restrict__ x, u16* __restrict__ xb) {
  int i = (blockIdx.x * 256 + threadIdx.x) * 4;
  const float4 v = *(const float4*)(x + i);
  u16x4 o = {f2bf(v.x), f2bf(v.y), f2bf(v.z), f2bf(v.w)};
  *(u16x4*)(xb + i) = o;
}

// Y[M,N] = X[M,K] @ W[N,K]^T, bf16 in, fp32 acc. 128x128 tile, BK=32,
// global_load_lds width-16 staging (m97 recipe), 4 waves 2x2, 4x4 mfma/wave.
template <int EPI>
__device__ __forceinline__ void gemm_body(
    const u16* __restrict__ X, const u16* __restrict__ Wb,
    float* __restrict__ Yf, u16* __restrict__ Qb, u16* __restrict__ Kb,
    u16* __restrict__ Vtb, int M, int N, int K) {
  __shared__ u16 As[128 * 32];
  __shared__ u16 Bs[128 * 32];
  const int t = threadIdx.x;
  const int lane = t & 63;
  const int w = t >> 6;
  const int quad = lane >> 4;
  const int l = lane & 15;
  const int wh = w >> 1;
  const int ww = w & 1;
  const int bm = blockIdx.y * 128;
  const int bn = blockIdx.x * 128;
  const int srow0 = 2 * w * 16 + (lane >> 2);
  const int scol = (lane & 3) * 8;  // u16
  const u16* gA = X + (size_t)(bm + srow0) * K + scol;
  const u16* gB = Wb + (size_t)(bn + srow0) * K + scol;
  const size_t segK = (size_t)16 * K;
  u16* lA0 = As + 2 * w * 512;
  u16* lA1 = lA0 + 512;
  u16* lB0 = Bs + 2 * w * 512;
  u16* lB1 = lB0 + 512;

  f32x4 acc[4][4];
#pragma unroll
  for (int i = 0; i < 4; ++i)
#pragma unroll
    for (int j = 0; j < 4; ++j) acc[i][j] = (f32x4){0.f, 0.f, 0.f, 0.f};

  for (int k0 = 0; k0 < K; k0 += 32) {
    __syncthreads();  // prev tile's ds_reads done
    glds16(gA + k0, lA0);
    glds16(gA + k0 + segK, lA1);
    glds16(gB + k0, lB0);
    glds16(gB + k0 + segK, lB1);
    __syncthreads();  // drains vmcnt -> staged data visible
    short8 af[4], bf[4];
#pragma unroll
    for (int mt = 0; mt < 4; ++mt)
      af[mt] = *(const short8*)&As[(wh * 64 + mt * 16 + l) * 32 + quad * 8];
#pragma unroll
    for (int nt = 0; nt < 4; ++nt)
      bf[nt] = *(const short8*)&Bs[(ww * 64 + nt * 16 + l) * 32 + quad * 8];
#pragma unroll
    for (int mt = 0; mt < 4; ++mt)
#pragma unroll
      for (int nt = 0; nt < 4; ++nt)
        acc[mt][nt] = __builtin_amdgcn_mfma_f32_16x16x32_bf16(
            af[mt], bf[nt], acc[mt][nt], 0, 0, 0);
  }
#pragma unroll
  for (int mt = 0; mt < 4; ++mt) {
#pragma unroll
    for (int nt = 0; nt < 4; ++nt) {
      const int m0 = bm + wh * 64 + mt * 16 + quad * 4;
      const int n = bn + ww * 64 + nt * 16 + l;
      if (EPI == 0) {
#pragma unroll
        for (int r = 0; r < 4; ++r)
          Yf[(size_t)(m0 + r) * N + n] = acc[mt][nt][r];
      } else {
        const int b = m0 >> 11;
        const int s0 = m0 & 2047;
        const int part = n >> 10;
        const int h = (n & 1023) >> 6;
        const int d = n & 63;
        if (part == 0) {
#pragma unroll
          for (int r = 0; r < 4; ++r)
            Qb[((size_t)(b * 16 + h) * 2048 + s0 + r) * 64 + d] =
                f2bf(acc[mt][nt][r]);
        } else if (part == 1) {
#pragma unroll
          for (int r = 0; r < 4; ++r)
            Kb[((size_t)(b * 16 + h) * 2048 + s0 + r) * 64 + d] =
                f2bf(acc[mt][nt][r]);
        } else {
          u16x4 pv = {f2bf(acc[mt][nt][0]), f2bf(acc[mt][nt][1]),
                      f2bf(acc[mt][nt][2]), f2bf(acc[mt][nt][3])};
          *(u16x4*)(Vtb + ((size_t)(b * 16 + h) * 64 + d) * 2048 + s0) = pv;
        }
      }
    }
  }
}

__global__ __launch_bounds__(256) void gemm_qkv(
    const u16* __restrict__ X, const u16* __restrict__ Wb,
    u16* __restrict__ Qb, u16* __restrict__ Kb, u16* __restrict__ Vtb) {
  gemm_body<1>(X, Wb, nullptr, Qb, Kb, Vtb, M_, N3_, D_);
}

__global__ __launch_bounds__(256) void gemm_out(
    const u16* __restrict__ X, const u16* __restrict__ Wb,
    float* __restrict__ Yf) {
  gemm_body<0>(X, Wb, Yf, nullptr, nullptr, nullptr, M_, D_, D_);
}

// Flash attention on MFMA — R2 structure, q-tile 64 (wave = 16 q-rows).
// Block = (b, q-tile 64, h); 256 thr / 4 waves; KV tile 64 in padded LDS.
__global__ __launch_bounds__(256) void attn_mfma(
    const u16* __restrict__ Qb, const u16* __restrict__ Kb,
    const u16* __restrict__ Vtb, const float* __restrict__ alibi,
    const float* __restrict__ pad, u16* __restrict__ ctxb) {
  __shared__ u16 KL[64][72];
  __shared__ u16 VL[64][72];
  __shared__ u16 PL[4][16][72];
  const int t = threadIdx.x;
  const int lane = t & 63;
  const int w = t >> 6;
  const int quad = lane >> 4;
  const int l = lane & 15;
  const int b = blockIdx.x;
  const int q0 = blockIdx.y * 64;
  const int h = blockIdx.z;
  const int bh = b * 16 + h;
  const int qw = q0 + w * 16;
  const int srow = t >> 2;       // staging row 0..63
  const int sq = (t & 3) * 16;   // staging col offset (u16)

  // Q fragments straight from global, reused across all KV tiles.
  short8 qf[2];
#pragma unroll
  for (int kq = 0; kq < 2; ++kq)
    qf[kq] = *(const short8*)(
        Qb + ((size_t)bh * 2048 + qw + l) * 64 + kq * 32 + quad * 8);

  f32x4 Ou[4];
  float mrun[4], lrun[4];
#pragma unroll
  for (int r = 0; r < 4; ++r) { mrun[r] = -1e30f; lrun[r] = 0.f; }
#pragma unroll
  for (int dn = 0; dn < 4; ++dn) Ou[dn] = (f32x4){0.f, 0.f, 0.f, 0.f};

  const u16* Kg = Kb + ((size_t)bh * 2048) * 64;
  const u16* Vg = Vtb + ((size_t)bh * 64) * 2048;

  for (int kt = 0; kt < S_ / 64; ++kt) {
    const int k0 = kt * 64;
    // global loads first (overlap with the barrier wait)
    const short8 kv0 = *(const short8*)(Kg + (size_t)(k0 + srow) * 64 + sq);
    const short8 kv1 = *(const short8*)(Kg + (size_t)(k0 + srow) * 64 + sq + 8);
    const short8 vv0 = *(const short8*)(Vg + (size_t)srow * 2048 + k0 + sq);
    const short8 vv1 = *(const short8*)(Vg + (size_t)srow * 2048 + k0 + sq + 8);
    __syncthreads();
    *(short8*)&KL[srow][sq] = kv0;
    *(short8*)&KL[srow][sq + 8] = kv1;
    *(short8*)&VL[srow][sq] = vv0;
    *(short8*)&VL[srow][sq + 8] = vv1;
    __syncthreads();

    // QK^T
    short8 kf[4][2];
#pragma unroll
    for (int nt = 0; nt < 4; ++nt)
#pragma unroll
      for (int kq = 0; kq < 2; ++kq)
        kf[nt][kq] = *(const short8*)&KL[nt * 16 + l][kq * 32 + quad * 8];
    f32x4 sc[4];
#pragma unroll
    for (int nt = 0; nt < 4; ++nt) {
      f32x4 c = {0.f, 0.f, 0.f, 0.f};
      c = __builtin_amdgcn_mfma_f32_16x16x32_bf16(qf[0], kf[nt][0], c, 0, 0, 0);
      c = __builtin_amdgcn_mfma_f32_16x16x32_bf16(qf[1], kf[nt][1], c, 0, 0, 0);
      sc[nt] = c;
    }

    // bias: *0.125 + alibi[h,q,k] + pad[b,k]
    float padv[4];
#pragma unroll
    for (int nt = 0; nt < 4; ++nt)
      padv[nt] = pad[(size_t)b * S_ + k0 + nt * 16 + l];
#pragma unroll
    for (int nt = 0; nt < 4; ++nt) {
      const float* ap =
          alibi + ((size_t)h * S_ + qw + quad * 4) * S_ + k0 + nt * 16 + l;
#pragma unroll
      for (int r = 0; r < 4; ++r)
        sc[nt][r] = fmaf(sc[nt][r], 0.125f, ap[(size_t)r * S_] + padv[nt]);
    }

    // online softmax per q-row (row = qw + quad*4 + r)
#pragma unroll
    for (int r = 0; r < 4; ++r) {
      float rm = fmaxf(fmaxf(sc[0][r], sc[1][r]), fmaxf(sc[2][r], sc[3][r]));
#pragma unroll
      for (int off = 1; off < 16; off <<= 1)
        rm = fmaxf(rm, __shfl_xor(rm, off, 16));
      const float mnew = fmaxf(mrun[r], rm);
      const float alpha = __expf(mrun[r] - mnew);
      mrun[r] = mnew;
      float rs = 0.f;
#pragma unroll
      for (int nt = 0; nt < 4; ++nt) {
        const float e = __expf(sc[nt][r] - mnew);
        sc[nt][r] = e;
        rs += e;
      }
#pragma unroll
      for (int off = 1; off < 16; off <<= 1) rs += __shfl_xor(rs, off, 16);
      lrun[r] = lrun[r] * alpha + rs;
#pragma unroll
      for (int dn = 0; dn < 4; ++dn) Ou[dn][r] *= alpha;
    }

    // P -> wave-private LDS (bf16), A-operand layout [q_local][key_local]
#pragma unroll
    for (int nt = 0; nt < 4; ++nt)
#pragma unroll
      for (int r = 0; r < 4; ++r)
        PL[w][quad * 4 + r][nt * 16 + l] = f2bf(sc[nt][r]);

    // PV (same-wave LDS write->read; in-order DS pipe, no barrier)
    short8 vf[4][2], pf[2];
#pragma unroll
    for (int dn = 0; dn < 4; ++dn)
#pragma unroll
      for (int kq = 0; kq < 2; ++kq)
        vf[dn][kq] = *(const short8*)&VL[dn * 16 + l][kq * 32 + quad * 8];
#pragma unroll
    for (int kq = 0; kq < 2; ++kq)
      pf[kq] = *(const short8*)&PL[w][l][kq * 32 + quad * 8];
#pragma unroll
    for (int dn = 0; dn < 4; ++dn) {
      Ou[dn] = __builtin_amdgcn_mfma_f32_16x16x32_bf16(
          pf[0], vf[dn][0], Ou[dn], 0, 0, 0);
      Ou[dn] = __builtin_amdgcn_mfma_f32_16x16x32_bf16(
          pf[1], vf[dn][1], Ou[dn], 0, 0, 0);
    }
  }

  // epilogue: ctx bf16 [b, s, h*64+d]
#pragma unroll
  for (int r = 0; r < 4; ++r) {
    const float inv = 1.0f / lrun[r];
    const int s = qw + quad * 4 + r;
#pragma unroll
    for (int dn = 0; dn < 4; ++dn)
      ctxb[((size_t)b * 2048 + s) * 1024 + h * 64 + dn * 16 + l] =
          f2bf(Ou[dn][r] * inv);
  }
}

extern "C" void kernel_launch(void* const* d_in, const int* in_sizes, int n_in,
                              void* d_out, int out_size, void* d_ws,
                              size_t ws_size, hipStream_t stream) {
  const float* x     = (const float*)d_in[0];
  const float* alibi = (const float*)d_in[1];
  const float* pad   = (const float*)d_in[2];
  const float* W_qkv = (const float*)d_in[3];
  const float* A_qkv = (const float*)d_in[4];
  const float* B_qkv = (const float*)d_in[5];
  const float* W_out = (const float*)d_in[6];
  const float* A_out = (const float*)d_in[7];
  const float* B_out = (const float*)d_in[8];
  float* out = (float*)d_out;

  u16* ws = (u16*)d_ws;
  u16* xb    = ws;                               // 4096*1024
  u16* weffq = xb + (size_t)M_ * D_;             // 3072*1024
  u16* weffo = weffq + (size_t)N3_ * D_;         // 1024*1024
  u16* Qb    = weffo + (size_t)D_ * D_;          // 2*16*2048*64
  u16* Kb    = Qb + (size_t)M_ * D_;
  u16* Vtb   = Kb + (size_t)M_ * D_;
  u16* ctxb  = Vtb + (size_t)M_ * D_;            // 4096*1024

  fold_kernel<<<(N3_ * D_) / 256, 256, 0, stream>>>(W_qkv, A_qkv, B_qkv, weffq,
                                                    N3_, D_);
  fold_kernel<<<(D_ * D_) / 256, 256, 0, stream>>>(W_out, A_out, B_out, weffo,
                                                   D_, D_);
  cvt_kernel<<<(M_ * D_) / 1024, 256, 0, stream>>>(x, xb);
  gemm_qkv<<<dim3(N3_ / 128, M_ / 128), 256, 0, stream>>>(xb, weffq, Qb, Kb,
                                                          Vtb);
  attn_mfma<<<dim3(B_, S_ / 64, H_), 256, 0, stream>>>(Qb, Kb, Vtb, alibi, pad,
                                                       ctxb);
  gemm_out<<<dim3(D_ / 128, M_ / 128), 256, 0, stream>>>(ctxb, weffo, out);
}

// Round 5
// 581.031 us; speedup vs baseline: 1.2605x; 1.0403x over previous
//
#include <hip/hip_runtime.h>

#define H_ 16
#define HD_ 64
#define S_ 2048
#define D_ 1024
#define B_ 2
#define R_ 32
#define M_ 4096   // B*S
#define N3_ 3072  // 3*D

typedef __attribute__((ext_vector_type(8))) short short8;
typedef __attribute__((ext_vector_type(4))) float f32x4;
typedef unsigned short u16;
typedef __attribute__((ext_vector_type(4))) unsigned short u16x4;

__device__ inline u16 f2bf(float f) {  // RNE float->bf16
  unsigned u = __float_as_uint(f);
  u += 0x7fff + ((u >> 16) & 1);
  return (u16)(u >> 16);
}

// async global->LDS, 16 B per lane; lds ptr must be wave-uniform.
__device__ __forceinline__ void glds16(const u16* g, u16* lds) {
  __builtin_amdgcn_global_load_lds(
      (const __attribute__((address_space(1))) unsigned int*)g,
      (__attribute__((address_space(3))) unsigned int*)lds, 16, 0, 0);
}

// Weff[o*IN+i] = W[o*IN+i] + (1/32) * sum_r A[i*R+r] * Bm[r*OUT+o], stored bf16
__global__ void fold_kernel(const float* __restrict__ W,
                            const float* __restrict__ A,
                            const float* __restrict__ Bm,
                            u16* __restrict__ out, int OUT, int IN) {
  int idx = blockIdx.x * 256 + threadIdx.x;
  int o = idx / IN;
  int i = idx - o * IN;
  float s = 0.f;
#pragma unroll
  for (int r = 0; r < R_; ++r) s += A[i * R_ + r] * Bm[r * OUT + o];
  out[idx] = f2bf(W[idx] + s * (1.0f / 32.0f));
}

__global__ void cvt_kernel(const float* __restrict__ x, u16* __restrict__ xb) {
  int i = (blockIdx.x * 256 + threadIdx.x) * 4;
  const float4 v = *(const float4*)(x + i);
  u16x4 o = {f2bf(v.x), f2bf(v.y), f2bf(v.z), f2bf(v.w)};
  *(u16x4*)(xb + i) = o;
}

// Y[M,N] = X[M,K] @ W[N,K]^T, bf16 in, fp32 acc. 128x128 tile, BK=32,
// global_load_lds width-16 staging (m97 recipe), 4 waves 2x2, 4x4 mfma/wave.
template <int EPI>
__device__ __forceinline__ void gemm_body(
    const u16* __restrict__ X, const u16* __restrict__ Wb,
    float* __restrict__ Yf, u16* __restrict__ Qb, u16* __restrict__ Kb,
    u16* __restrict__ Vtb, int M, int N, int K) {
  __shared__ u16 As[128 * 32];
  __shared__ u16 Bs[128 * 32];
  const int t = threadIdx.x;
  const int lane = t & 63;
  const int w = t >> 6;
  const int quad = lane >> 4;
  const int l = lane & 15;
  const int wh = w >> 1;
  const int ww = w & 1;
  const int bm = blockIdx.y * 128;
  const int bn = blockIdx.x * 128;
  const int srow0 = 2 * w * 16 + (lane >> 2);
  const int scol = (lane & 3) * 8;  // u16
  const u16* gA = X + (size_t)(bm + srow0) * K + scol;
  const u16* gB = Wb + (size_t)(bn + srow0) * K + scol;
  const size_t segK = (size_t)16 * K;
  u16* lA0 = As + 2 * w * 512;
  u16* lA1 = lA0 + 512;
  u16* lB0 = Bs + 2 * w * 512;
  u16* lB1 = lB0 + 512;

  f32x4 acc[4][4];
#pragma unroll
  for (int i = 0; i < 4; ++i)
#pragma unroll
    for (int j = 0; j < 4; ++j) acc[i][j] = (f32x4){0.f, 0.f, 0.f, 0.f};

  for (int k0 = 0; k0 < K; k0 += 32) {
    __syncthreads();  // prev tile's ds_reads done
    glds16(gA + k0, lA0);
    glds16(gA + k0 + segK, lA1);
    glds16(gB + k0, lB0);
    glds16(gB + k0 + segK, lB1);
    __syncthreads();  // drains vmcnt -> staged data visible
    short8 af[4], bf[4];
#pragma unroll
    for (int mt = 0; mt < 4; ++mt)
      af[mt] = *(const short8*)&As[(wh * 64 + mt * 16 + l) * 32 + quad * 8];
#pragma unroll
    for (int nt = 0; nt < 4; ++nt)
      bf[nt] = *(const short8*)&Bs[(ww * 64 + nt * 16 + l) * 32 + quad * 8];
#pragma unroll
    for (int mt = 0; mt < 4; ++mt)
#pragma unroll
      for (int nt = 0; nt < 4; ++nt)
        acc[mt][nt] = __builtin_amdgcn_mfma_f32_16x16x32_bf16(
            af[mt], bf[nt], acc[mt][nt], 0, 0, 0);
  }
#pragma unroll
  for (int mt = 0; mt < 4; ++mt) {
#pragma unroll
    for (int nt = 0; nt < 4; ++nt) {
      const int m0 = bm + wh * 64 + mt * 16 + quad * 4;
      const int n = bn + ww * 64 + nt * 16 + l;
      if (EPI == 0) {
#pragma unroll
        for (int r = 0; r < 4; ++r)
          Yf[(size_t)(m0 + r) * N + n] = acc[mt][nt][r];
      } else {
        const int b = m0 >> 11;
        const int s0 = m0 & 2047;
        const int part = n >> 10;
        const int h = (n & 1023) >> 6;
        const int d = n & 63;
        if (part == 0) {
#pragma unroll
          for (int r = 0; r < 4; ++r)
            Qb[((size_t)(b * 16 + h) * 2048 + s0 + r) * 64 + d] =
                f2bf(acc[mt][nt][r]);
        } else if (part == 1) {
#pragma unroll
          for (int r = 0; r < 4; ++r)
            Kb[((size_t)(b * 16 + h) * 2048 + s0 + r) * 64 + d] =
                f2bf(acc[mt][nt][r]);
        } else {
          u16x4 pv = {f2bf(acc[mt][nt][0]), f2bf(acc[mt][nt][1]),
                      f2bf(acc[mt][nt][2]), f2bf(acc[mt][nt][3])};
          *(u16x4*)(Vtb + ((size_t)(b * 16 + h) * 64 + d) * 2048 + s0) = pv;
        }
      }
    }
  }
}

__global__ __launch_bounds__(256) void gemm_qkv(
    const u16* __restrict__ X, const u16* __restrict__ Wb,
    u16* __restrict__ Qb, u16* __restrict__ Kb, u16* __restrict__ Vtb) {
  gemm_body<1>(X, Wb, nullptr, Qb, Kb, Vtb, M_, N3_, D_);
}

__global__ __launch_bounds__(256) void gemm_out(
    const u16* __restrict__ X, const u16* __restrict__ Wb,
    float* __restrict__ Yf) {
  gemm_body<0>(X, Wb, Yf, nullptr, nullptr, nullptr, M_, D_, D_);
}

// Flash attention, MFMA, batch-fused 512-thread blocks, fixed-max softmax.
// Block = (q-tile 64, h); 8 waves = 4 q-stripes x 2 batches.
// Fixed m=12: softmax = exp(s-12)/sum exp(s-12) -- mathematically exact,
// no running max/rescale. Row sums via P @ ones MFMA.
__global__ __launch_bounds__(512) void attn_mfma2(
    const u16* __restrict__ Qb, const u16* __restrict__ Kb,
    const u16* __restrict__ Vtb, const float* __restrict__ alibi,
    const float* __restrict__ pad, u16* __restrict__ ctxb) {
  __shared__ u16 KL[2][64][72];
  __shared__ u16 VL[2][64][72];
  __shared__ u16 PL[8][16][72];
  const int t = threadIdx.x;
  const int lane = t & 63;
  const int w = t >> 6;            // 0..7
  const int quad = lane >> 4;
  const int l = lane & 15;
  const int q0 = blockIdx.x * 64;
  const int h = blockIdx.y;
  const int b = w & 1;             // wave's batch
  const int qsub = w >> 1;         // wave's q-stripe 0..3
  const int qw = q0 + qsub * 16;

  // staging role: 2-wave groups own one of K0,K1,V0,V1 (wave-uniform)
  const int tile = t >> 7;         // 0..3
  const int sub = t & 127;
  const int srow = sub >> 1;       // 0..63
  const int scolh = (sub & 1) * 32;  // u16 offset, 32 u16 = 64 B per thread
  const int sb = tile & 1;
  const u16* gK = Kb + ((size_t)(sb * 16 + h) * 2048) * 64;
  const u16* gV = Vtb + ((size_t)(sb * 16 + h) * 64 + srow) * 2048;

  // Q fragments for this wave's (b, q-stripe)
  short8 qf[2];
#pragma unroll
  for (int kq = 0; kq < 2; ++kq)
    qf[kq] = *(const short8*)(
        Qb + ((size_t)(b * 16 + h) * 2048 + qw + l) * 64 + kq * 32 + quad * 8);

  const short8 ones = {0x3F80, 0x3F80, 0x3F80, 0x3F80,
                       0x3F80, 0x3F80, 0x3F80, 0x3F80};  // bf16 1.0

  f32x4 Ou[4];
  f32x4 Lacc = {0.f, 0.f, 0.f, 0.f};
#pragma unroll
  for (int dn = 0; dn < 4; ++dn) Ou[dn] = (f32x4){0.f, 0.f, 0.f, 0.f};

  const float* ap0 = alibi + ((size_t)h * S_ + qw + quad * 4) * S_ + l;
  const float* pp0 = pad + (size_t)b * S_ + l;

  for (int kt = 0; kt < S_ / 64; ++kt) {
    const int k0 = kt * 64;
    // staging loads first (overlap with barrier wait)
    short8 st[4];
    if (tile < 2) {
#pragma unroll
      for (int j = 0; j < 4; ++j)
        st[j] = *(const short8*)(gK + (size_t)(k0 + srow) * 64 + scolh + j * 8);
    } else {
#pragma unroll
      for (int j = 0; j < 4; ++j)
        st[j] = *(const short8*)(gV + k0 + scolh + j * 8);
    }
    __syncthreads();  // prev tile's ds_reads done
    {
      u16* dst = (tile < 2) ? &KL[sb][srow][scolh] : &VL[sb][srow][scolh];
#pragma unroll
      for (int j = 0; j < 4; ++j) *(short8*)(dst + j * 8) = st[j];
    }
    __syncthreads();  // staged data visible

    // QK^T
    short8 kf[4][2];
#pragma unroll
    for (int nt = 0; nt < 4; ++nt)
#pragma unroll
      for (int kq = 0; kq < 2; ++kq)
        kf[nt][kq] = *(const short8*)&KL[b][nt * 16 + l][kq * 32 + quad * 8];
    f32x4 sc[4];
#pragma unroll
    for (int nt = 0; nt < 4; ++nt) {
      f32x4 c = {0.f, 0.f, 0.f, 0.f};
      c = __builtin_amdgcn_mfma_f32_16x16x32_bf16(qf[0], kf[nt][0], c, 0, 0, 0);
      c = __builtin_amdgcn_mfma_f32_16x16x32_bf16(qf[1], kf[nt][1], c, 0, 0, 0);
      sc[nt] = c;
    }

    // P = exp(qk*0.125 + alibi + pad - 12); store to wave-private LDS
#pragma unroll
    for (int nt = 0; nt < 4; ++nt) {
      const float pv = pp0[k0 + nt * 16] - 12.0f;
      const float* ap = ap0 + k0 + nt * 16;
#pragma unroll
      for (int r = 0; r < 4; ++r) {
        const float e = __expf(fmaf(sc[nt][r], 0.125f, ap[(size_t)r * S_] + pv));
        PL[w][quad * 4 + r][nt * 16 + l] = f2bf(e);
      }
    }

    // PV + row-sum (same-wave LDS write->read; in-order DS pipe, no barrier)
    short8 vf[4][2], pf[2];
#pragma unroll
    for (int dn = 0; dn < 4; ++dn)
#pragma unroll
      for (int kq = 0; kq < 2; ++kq)
        vf[dn][kq] = *(const short8*)&VL[b][dn * 16 + l][kq * 32 + quad * 8];
#pragma unroll
    for (int kq = 0; kq < 2; ++kq)
      pf[kq] = *(const short8*)&PL[w][l][kq * 32 + quad * 8];
#pragma unroll
    for (int dn = 0; dn < 4; ++dn) {
      Ou[dn] = __builtin_amdgcn_mfma_f32_16x16x32_bf16(
          pf[0], vf[dn][0], Ou[dn], 0, 0, 0);
      Ou[dn] = __builtin_amdgcn_mfma_f32_16x16x32_bf16(
          pf[1], vf[dn][1], Ou[dn], 0, 0, 0);
    }
    Lacc = __builtin_amdgcn_mfma_f32_16x16x32_bf16(pf[0], ones, Lacc, 0, 0, 0);
    Lacc = __builtin_amdgcn_mfma_f32_16x16x32_bf16(pf[1], ones, Lacc, 0, 0, 0);
  }

  // epilogue: ctx bf16 [b, s, h*64+d]; every lane's Lacc[r] = row sum
#pragma unroll
  for (int r = 0; r < 4; ++r) {
    const float inv = 1.0f / Lacc[r];
    const int s = qw + quad * 4 + r;
#pragma unroll
    for (int dn = 0; dn < 4; ++dn)
      ctxb[((size_t)b * 2048 + s) * 1024 + h * 64 + dn * 16 + l] =
          f2bf(Ou[dn][r] * inv);
  }
}

extern "C" void kernel_launch(void* const* d_in, const int* in_sizes, int n_in,
                              void* d_out, int out_size, void* d_ws,
                              size_t ws_size, hipStream_t stream) {
  const float* x     = (const float*)d_in[0];
  const float* alibi = (const float*)d_in[1];
  const float* pad   = (const float*)d_in[2];
  const float* W_qkv = (const float*)d_in[3];
  const float* A_qkv = (const float*)d_in[4];
  const float* B_qkv = (const float*)d_in[5];
  const float* W_out = (const float*)d_in[6];
  const float* A_out = (const float*)d_in[7];
  const float* B_out = (const float*)d_in[8];
  float* out = (float*)d_out;

  u16* ws = (u16*)d_ws;
  u16* xb    = ws;                               // 4096*1024
  u16* weffq = xb + (size_t)M_ * D_;             // 3072*1024
  u16* weffo = weffq + (size_t)N3_ * D_;         // 1024*1024
  u16* Qb    = weffo + (size_t)D_ * D_;          // 2*16*2048*64
  u16* Kb    = Qb + (size_t)M_ * D_;
  u16* Vtb   = Kb + (size_t)M_ * D_;
  u16* ctxb  = Vtb + (size_t)M_ * D_;            // 4096*1024

  fold_kernel<<<(N3_ * D_) / 256, 256, 0, stream>>>(W_qkv, A_qkv, B_qkv, weffq,
                                                    N3_, D_);
  fold_kernel<<<(D_ * D_) / 256, 256, 0, stream>>>(W_out, A_out, B_out, weffo,
                                                   D_, D_);
  cvt_kernel<<<(M_ * D_) / 1024, 256, 0, stream>>>(x, xb);
  gemm_qkv<<<dim3(N3_ / 128, M_ / 128), 256, 0, stream>>>(xb, weffq, Qb, Kb,
                                                          Vtb);
  attn_mfma2<<<dim3(S_ / 64, H_), 512, 0, stream>>>(Qb, Kb, Vtb, alibi, pad,
                                                    ctxb);
  gemm_out<<<dim3(D_ / 128, M_ / 128), 256, 0, stream>>>(ctxb, weffo, out);
}